// Round 5
// baseline (97.201 us; speedup 1.0000x reference)
//
#include <hip/hip_runtime.h>

#define NPTS  4096
#define NB    8
#define TOT   (2 * NB * NPTS)      // 65536 A points across both directions
#define THR   128                  // threads per block (2 waves)
#define APT   16                   // A points per thread
#define APB   (THR * APT)          // 2048 A points per block
#define AUNITS (TOT / APB)         // 32
#define BCH   16                   // B chunks per cloud
#define BCHP  (NPTS / BCH)         // 256 B points per chunk

// packed[0..32767] = x clouds, packed[32768..65535] = y clouds,
// each entry (p0,p1,p2, h = -0.5*|p|^2).
// min_j d = -2 * (max_j s + h_a),  s = dot(a,b) + h_b

// ---------------- pass 0: pack + init smax + zero out ----------------
__global__ __launch_bounds__(256) void prep_kernel(
    const float* __restrict__ x, const float* __restrict__ y,
    float4* __restrict__ packed, unsigned* __restrict__ smax,
    float* __restrict__ out)
{
    int i = blockIdx.x * 256 + threadIdx.x;          // 0..65535
    const float* src = (i < NB * NPTS) ? x : y;
    int j = (i < NB * NPTS) ? i : i - NB * NPTS;
    float p0 = src[3 * j + 0];
    float p1 = src[3 * j + 1];
    float p2 = src[3 * j + 2];
    packed[i] = make_float4(p0, p1, p2,
                            -0.5f * (p0 * p0 + p1 * p1 + p2 * p2));
    smax[i] = 0u;        // below any order-mapped finite float
    if (i == 0) *out = 0.f;
}

// ---------------- pass 1: partial max over a 256-pt B chunk ----------------
// grid = AUNITS * BCH = 512 blocks of 128 threads, 2 blocks/CU.
__global__ __launch_bounds__(THR) void chamfer_main(
    const float4* __restrict__ packed,
    unsigned* __restrict__ smax)
{
    __shared__ float4 sB[BCHP];   // 4 KB

    const int bid   = blockIdx.x;
    const int bCh   = bid & (BCH - 1);
    const int aU    = bid >> 4;
    const int aBase = aU * APB;                  // global A index base
    const int dir   = aBase >> 15;               // 0: A=x, 1: A=y
    const int b     = (aBase >> 12) & 7;

    const float4* __restrict__ Bb =
        packed + (dir ? (b * NPTS) : (NB * NPTS + b * NPTS));
    const float4* __restrict__ Bc = Bb + bCh * BCHP;

    const int tid = threadIdx.x;

    // stage B chunk (coalesced dwordx4 -> ds_write_b128)
    #pragma unroll
    for (int k = 0; k < BCHP / THR; ++k)
        sB[k * THR + tid] = Bc[k * THR + tid];

    // own A points (coalesced dwordx4)
    float a0[APT], a1[APT], a2[APT], m[APT];
    #pragma unroll
    for (int k = 0; k < APT; ++k) {
        float4 A = packed[aBase + k * THR + tid];
        a0[k] = A.x; a1[k] = A.y; a2[k] = A.z;
        m[k] = -3e38f;
    }

    __syncthreads();

    // 4 B points per iter: 4 ds_read_b128 in flight, 16*14 = 224 VALU insts
    // between LDS waits -> LDS latency + issue fully hidden under VALU.
    for (int j = 0; j < BCHP; j += 4) {
        float4 qa = sB[j];
        float4 qb = sB[j + 1];
        float4 qc = sB[j + 2];
        float4 qd = sB[j + 3];
        #pragma unroll
        for (int k = 0; k < APT; ++k) {
            float sa = fmaf(a0[k], qa.x, fmaf(a1[k], qa.y, fmaf(a2[k], qa.z, qa.w)));
            float sb = fmaf(a0[k], qb.x, fmaf(a1[k], qb.y, fmaf(a2[k], qb.z, qb.w)));
            float sc = fmaf(a0[k], qc.x, fmaf(a1[k], qc.y, fmaf(a2[k], qc.z, qc.w)));
            float sd = fmaf(a0[k], qd.x, fmaf(a1[k], qd.y, fmaf(a2[k], qd.z, qd.w)));
            m[k] = fmaxf(fmaxf(sa, sb), m[k]);   // v_max3_f32
            m[k] = fmaxf(fmaxf(sc, sd), m[k]);   // v_max3_f32
        }
    }

    // order-preserving float->uint map (handles negatives), atomic combine
    #pragma unroll
    for (int k = 0; k < APT; ++k) {
        unsigned bits = __float_as_uint(m[k]);
        unsigned u = (bits & 0x80000000u) ? ~bits : (bits | 0x80000000u);
        atomicMax(&smax[aBase + k * THR + tid], u);
    }
}

// ---------------- pass 2: unmap, add h_a, sum ----------------
__global__ __launch_bounds__(256) void reduce_kernel(
    const unsigned* __restrict__ smax,
    const float4* __restrict__ packed,
    float* __restrict__ out)
{
    const int stride = 64 * 256;
    int tid = blockIdx.x * 256 + threadIdx.x;
    float s = 0.f;
    for (int k = tid; k < TOT; k += stride) {
        unsigned u = smax[k];
        unsigned bits = (u & 0x80000000u) ? (u & 0x7FFFFFFFu) : ~u;
        s += __uint_as_float(bits) + packed[k].w;    // smax + h_a
    }

    #pragma unroll
    for (int off = 32; off > 0; off >>= 1)
        s += __shfl_down(s, off);

    __shared__ float red[4];
    const int lane = threadIdx.x & 63, wave = threadIdx.x >> 6;
    if (lane == 0) red[wave] = s;
    __syncthreads();
    if (threadIdx.x == 0) {
        float t = red[0] + red[1] + red[2] + red[3];
        // loss contribution: -2*(smax+h_a) summed, * 0.005 / 32768
        atomicAdd(out, t * (-2.0f * 0.005f / 32768.f));
    }
}

extern "C" void kernel_launch(void* const* d_in, const int* in_sizes, int n_in,
                              void* d_out, int out_size, void* d_ws, size_t ws_size,
                              hipStream_t stream) {
    const float* x = (const float*)d_in[0];
    const float* y = (const float*)d_in[1];
    float* out = (float*)d_out;

    float4*   packed = (float4*)d_ws;                               // 1 MB
    unsigned* smax   = (unsigned*)((char*)d_ws + (size_t)TOT * 16); // 256 KB

    prep_kernel<<<dim3(TOT / 256), dim3(256), 0, stream>>>(x, y, packed, smax, out);
    chamfer_main<<<dim3(AUNITS * BCH), dim3(THR), 0, stream>>>(packed, smax);
    reduce_kernel<<<dim3(64), dim3(256), 0, stream>>>(smax, packed, out);
}

// Round 6
// 95.704 us; speedup vs baseline: 1.0156x; 1.0156x over previous
//
#include <hip/hip_runtime.h>

#define NPTS  4096
#define NB    8
#define TOT   (2 * NB * NPTS)      // 65536 A points across both directions
#define THR   128                  // threads per block (2 waves)
#define APT   16                   // A points per thread
#define APB   (THR * APT)          // 2048 A points per block
#define AUNITS (TOT / APB)         // 32
#define BCH   16                   // B chunks per cloud
#define BCHP  (NPTS / BCH)         // 256 B points per chunk

// packed[0..32767] = x clouds, packed[32768..65535] = y clouds,
// each entry (p0,p1,p2, h = -0.5*|p|^2).
// min_j d = -2 * (max_j s + h_a),  s = dot(a,b) + h_b

// ---------------- pass 0: pack + init smax + zero out ----------------
__global__ __launch_bounds__(256) void prep_kernel(
    const float* __restrict__ x, const float* __restrict__ y,
    float4* __restrict__ packed, unsigned* __restrict__ smax,
    float* __restrict__ out)
{
    int i = blockIdx.x * 256 + threadIdx.x;          // 0..65535
    const float* src = (i < NB * NPTS) ? x : y;
    int j = (i < NB * NPTS) ? i : i - NB * NPTS;
    float p0 = src[3 * j + 0];
    float p1 = src[3 * j + 1];
    float p2 = src[3 * j + 2];
    packed[i] = make_float4(p0, p1, p2,
                            -0.5f * (p0 * p0 + p1 * p1 + p2 * p2));
    smax[i] = 0u;        // below any order-mapped finite float
    if (i == 0) *out = 0.f;
}

// ---------------- pass 1: partial max over a 256-pt B chunk ----------------
// grid = AUNITS * BCH = 512 blocks of 128 threads, 2 blocks/CU.
// __launch_bounds__(128, 1): we run 1 wave/SIMD by design — give the
// allocator the full VGPR budget so the 64-reg A/m arrays do NOT spill
// (R5's VGPR=56 + scratch spill was the 44 us regression).
__global__ __launch_bounds__(THR, 1) void chamfer_main(
    const float4* __restrict__ packed,
    unsigned* __restrict__ smax)
{
    __shared__ float4 sB[BCHP];   // 4 KB

    const int bid   = blockIdx.x;
    const int bCh   = bid & (BCH - 1);
    const int aU    = bid >> 4;
    const int aBase = aU * APB;                  // global A index base
    const int dir   = aBase >> 15;               // 0: A=x, 1: A=y
    const int b     = (aBase >> 12) & 7;

    const float4* __restrict__ Bb =
        packed + (dir ? (b * NPTS) : (NB * NPTS + b * NPTS));
    const float4* __restrict__ Bc = Bb + bCh * BCHP;

    const int tid = threadIdx.x;

    // stage B chunk (coalesced dwordx4 -> ds_write_b128)
    #pragma unroll
    for (int k = 0; k < BCHP / THR; ++k)
        sB[k * THR + tid] = Bc[k * THR + tid];

    // own A points (coalesced dwordx4)
    float a0[APT], a1[APT], a2[APT], m[APT];
    #pragma unroll
    for (int k = 0; k < APT; ++k) {
        float4 A = packed[aBase + k * THR + tid];
        a0[k] = A.x; a1[k] = A.y; a2[k] = A.z;
        m[k] = -3e38f;
    }

    __syncthreads();

    // unroll 2 -> 8 ds_read_b128 in flight per ~450 VALU cycles:
    // enough ILP for 1 wave/SIMD to hide LDS latency entirely.
    #pragma unroll 2
    for (int j = 0; j < BCHP; j += 4) {
        float4 qa = sB[j];
        float4 qb = sB[j + 1];
        float4 qc = sB[j + 2];
        float4 qd = sB[j + 3];
        #pragma unroll
        for (int k = 0; k < APT; ++k) {
            float sa = fmaf(a0[k], qa.x, fmaf(a1[k], qa.y, fmaf(a2[k], qa.z, qa.w)));
            float sb = fmaf(a0[k], qb.x, fmaf(a1[k], qb.y, fmaf(a2[k], qb.z, qb.w)));
            float sc = fmaf(a0[k], qc.x, fmaf(a1[k], qc.y, fmaf(a2[k], qc.z, qc.w)));
            float sd = fmaf(a0[k], qd.x, fmaf(a1[k], qd.y, fmaf(a2[k], qd.z, qd.w)));
            m[k] = fmaxf(fmaxf(sa, sb), m[k]);   // v_max3_f32
            m[k] = fmaxf(fmaxf(sc, sd), m[k]);   // v_max3_f32
        }
    }

    // order-preserving float->uint map (handles negatives), atomic combine
    #pragma unroll
    for (int k = 0; k < APT; ++k) {
        unsigned bits = __float_as_uint(m[k]);
        unsigned u = (bits & 0x80000000u) ? ~bits : (bits | 0x80000000u);
        atomicMax(&smax[aBase + k * THR + tid], u);
    }
}

// ---------------- pass 2: unmap, add h_a, sum ----------------
__global__ __launch_bounds__(256) void reduce_kernel(
    const unsigned* __restrict__ smax,
    const float4* __restrict__ packed,
    float* __restrict__ out)
{
    const int stride = 64 * 256;
    int tid = blockIdx.x * 256 + threadIdx.x;
    float s = 0.f;
    for (int k = tid; k < TOT; k += stride) {
        unsigned u = smax[k];
        unsigned bits = (u & 0x80000000u) ? (u & 0x7FFFFFFFu) : ~u;
        s += __uint_as_float(bits) + packed[k].w;    // smax + h_a
    }

    #pragma unroll
    for (int off = 32; off > 0; off >>= 1)
        s += __shfl_down(s, off);

    __shared__ float red[4];
    const int lane = threadIdx.x & 63, wave = threadIdx.x >> 6;
    if (lane == 0) red[wave] = s;
    __syncthreads();
    if (threadIdx.x == 0) {
        float t = red[0] + red[1] + red[2] + red[3];
        // loss contribution: -2*(smax+h_a) summed, * 0.005 / 32768
        atomicAdd(out, t * (-2.0f * 0.005f / 32768.f));
    }
}

extern "C" void kernel_launch(void* const* d_in, const int* in_sizes, int n_in,
                              void* d_out, int out_size, void* d_ws, size_t ws_size,
                              hipStream_t stream) {
    const float* x = (const float*)d_in[0];
    const float* y = (const float*)d_in[1];
    float* out = (float*)d_out;

    float4*   packed = (float4*)d_ws;                               // 1 MB
    unsigned* smax   = (unsigned*)((char*)d_ws + (size_t)TOT * 16); // 256 KB

    prep_kernel<<<dim3(TOT / 256), dim3(256), 0, stream>>>(x, y, packed, smax, out);
    chamfer_main<<<dim3(AUNITS * BCH), dim3(THR), 0, stream>>>(packed, smax);
    reduce_kernel<<<dim3(64), dim3(256), 0, stream>>>(smax, packed, out);
}

// Round 7
// 86.514 us; speedup vs baseline: 1.1235x; 1.1062x over previous
//
#include <hip/hip_runtime.h>

#define NPTS 4096
#define NB   8
#define TOT  (2 * NB * NPTS)   // 65536 (i, dir*batch*point) rows

typedef __attribute__((ext_vector_type(8)))  short          bf16x8;
typedef __attribute__((ext_vector_type(8)))  unsigned short u16x8;
typedef __attribute__((ext_vector_type(16))) float          f32x16;

__device__ __forceinline__ unsigned short bf16_rne(float f) {
    unsigned u = __float_as_uint(f);
    u += 0x7FFFu + ((u >> 16) & 1u);
    return (unsigned short)(u >> 16);
}
__device__ __forceinline__ float bf16_f(unsigned short s) {
    return __uint_as_float(((unsigned)s) << 16);
}

// ---------------- pass 0: build fragment-ordered extended bf16 tiles -------
// s(i,j) = ah_i.bh_j + al_i.bh_j + ah_i.bl_j + 1*hh_j + 1*hl_j   (11 K-slots)
// A-ext slots: [ah0,ah1,ah2, al0,al1,al2, ah0,ah1 | ah2, 1, 1, 0,0,0,0,0]
// B-ext slots: [bh0,bh1,bh2, bh0,bh1,bh2, bl0,bl1 | bl2, hh, hl, 0,0,0,0,0]
// Storage (per cloud, 4096 pts): tile u (32 pts): u*1024 + g*512 + pos*16
// = exactly the 32x32x16 MFMA operand layout: lane l reads point (32u + (l&31)),
// k-slots 8*(l>>5)..+7, as one coalesced 16B chunk.
__global__ __launch_bounds__(256) void prep_kernel(
    const float* __restrict__ x, const float* __restrict__ y,
    unsigned short* __restrict__ Aform, unsigned short* __restrict__ Bform,
    float* __restrict__ h32, unsigned* __restrict__ smax,
    float* __restrict__ out)
{
    int i   = blockIdx.x * 256 + threadIdx.x;   // 0..65535
    int cid = i >> 12;                          // 0..7: x[b], 8..15: y[b]
    int p   = i & 4095;
    const float* src = (cid < 8) ? x + ((size_t)cid * NPTS + p) * 3
                                 : y + ((size_t)(cid - 8) * NPTS + p) * 3;
    float c0 = src[0], c1 = src[1], c2 = src[2];
    float h  = -0.5f * (c0 * c0 + c1 * c1 + c2 * c2);

    unsigned short h0 = bf16_rne(c0), h1 = bf16_rne(c1), h2 = bf16_rne(c2);
    unsigned short l0 = bf16_rne(c0 - bf16_f(h0));
    unsigned short l1 = bf16_rne(c1 - bf16_f(h1));
    unsigned short l2 = bf16_rne(c2 - bf16_f(h2));
    unsigned short hh = bf16_rne(h);
    unsigned short hl = bf16_rne(h - bf16_f(hh));
    const unsigned short ONE = 0x3F80;

    u16x8 alo, ahi, blo, bhi;
    alo[0]=h0; alo[1]=h1; alo[2]=h2; alo[3]=l0; alo[4]=l1; alo[5]=l2; alo[6]=h0; alo[7]=h1;
    ahi[0]=h2; ahi[1]=ONE; ahi[2]=ONE; ahi[3]=0; ahi[4]=0; ahi[5]=0; ahi[6]=0; ahi[7]=0;
    blo[0]=h0; blo[1]=h1; blo[2]=h2; blo[3]=h0; blo[4]=h1; blo[5]=h2; blo[6]=l0; blo[7]=l1;
    bhi[0]=l2; bhi[1]=hh; bhi[2]=hl; bhi[3]=0; bhi[4]=0; bhi[5]=0; bhi[6]=0; bhi[7]=0;

    int u = p >> 5, pos = p & 31;
    size_t base = ((size_t)cid << 17) + (size_t)u * 1024 + (size_t)pos * 16;
    *(u16x8*)((char*)Aform + base)       = alo;
    *(u16x8*)((char*)Aform + base + 512) = ahi;
    *(u16x8*)((char*)Bform + base)       = blo;
    *(u16x8*)((char*)Bform + base + 512) = bhi;

    h32[i]  = h;     // fp32 h_a for the epilogue (full precision)
    smax[i] = 0u;    // below any order-mapped float
    if (i == 0) *out = 0.f;
}

// ---------------- pass 1: MFMA chamfer core ----------------
// grid = 16 (dir,b) * 8 i-blocks * 4 j-quarters = 512 blocks of 256 thr.
// Wave owns 4 i-tiles (128 rows), loops 32 j-tiles (j-quarter) in pairs:
// d = mfma_32x32x16_bf16(Afrag, Bfrag, 0); run = max3(run, d0, d1).
__global__ __launch_bounds__(256, 2) void chamfer_mfma(
    const unsigned short* __restrict__ Aform,
    const unsigned short* __restrict__ Bform,
    unsigned* __restrict__ smax)
{
    __shared__ float red[512][33];   // 512 block-rows x 32 cols, +1 pad

    const int bid  = blockIdx.x;
    const int dirb = bid >> 5;        // 0..15 (A-cloud id)
    const int sub  = bid & 31;
    const int iblk = sub >> 2;        // 0..7
    const int jq   = sub & 3;         // 0..3
    const int bcld = dirb ^ 8;        // B-cloud id (x<->y)

    const int tid = threadIdx.x;
    const int w   = tid >> 6;         // wave 0..3
    const int l   = tid & 63;
    const int g   = l >> 5;           // k-half
    const int pos = l & 31;           // row/col within tile

    const char* Abase = (const char*)Aform + ((size_t)dirb << 17);
    const char* Bbase = (const char*)Bform + ((size_t)bcld << 17);

    // A fragments: i-tiles iblk*16 + w*4 + t (loaded once, reused for all j)
    const int it0 = iblk * 16 + w * 4;
    bf16x8 afr[4];
    #pragma unroll
    for (int t = 0; t < 4; ++t)
        afr[t] = *(const bf16x8*)(Abase + (size_t)(it0 + t) * 1024
                                        + (size_t)g * 512 + (size_t)pos * 16);

    f32x16 zc;
    #pragma unroll
    for (int r = 0; r < 16; ++r) zc[r] = 0.f;

    f32x16 run[4];
    #pragma unroll
    for (int t = 0; t < 4; ++t)
        #pragma unroll
        for (int r = 0; r < 16; ++r) run[t][r] = -3.0e38f;

    const char* Bq = Bbase + (size_t)(jq * 32) * 1024
                           + (size_t)g * 512 + (size_t)pos * 16;
    #pragma unroll 2
    for (int j = 0; j < 32; j += 2) {
        bf16x8 b0 = *(const bf16x8*)(Bq + (size_t)j * 1024);
        bf16x8 b1 = *(const bf16x8*)(Bq + (size_t)j * 1024 + 1024);
        #pragma unroll
        for (int t = 0; t < 4; ++t) {
            f32x16 d0 = __builtin_amdgcn_mfma_f32_32x32x16_bf16(afr[t], b0, zc, 0, 0, 0);
            f32x16 d1 = __builtin_amdgcn_mfma_f32_32x32x16_bf16(afr[t], b1, zc, 0, 0, 0);
            #pragma unroll
            for (int r = 0; r < 16; ++r)
                run[t][r] = fmaxf(fmaxf(d0[r], d1[r]), run[t][r]);   // v_max3_f32
        }
    }

    // scatter running maxes to LDS: row = C/D layout row, col = lane&31
    #pragma unroll
    for (int t = 0; t < 4; ++t)
        #pragma unroll
        for (int r = 0; r < 16; ++r) {
            int rowin = (r & 3) + 8 * (r >> 2) + 4 * g;   // verified C/D map
            red[(w * 4 + t) * 32 + rowin][pos] = run[t][r];
        }
    __syncthreads();

    // row-max over 32 cols; combine j-quarters via atomicMax (order-mapped)
    #pragma unroll
    for (int rr = 0; rr < 2; ++rr) {
        int r_blk = tid + rr * 256;
        float m = red[r_blk][0];
        #pragma unroll
        for (int k = 1; k < 32; ++k) m = fmaxf(m, red[r_blk][k]);
        int tile_local = r_blk >> 5, rowin = r_blk & 31;
        int idx = dirb * 4096 + (iblk * 16 + tile_local) * 32 + rowin;
        unsigned bits = __float_as_uint(m);
        unsigned mu = (bits & 0x80000000u) ? ~bits : (bits | 0x80000000u);
        atomicMax(&smax[idx], mu);
    }
}

// ---------------- pass 2: unmap, add h_a, sum ----------------
__global__ __launch_bounds__(256) void reduce_kernel(
    const unsigned* __restrict__ smax,
    const float* __restrict__ h32,
    float* __restrict__ out)
{
    const int stride = 64 * 256;
    int tid = blockIdx.x * 256 + threadIdx.x;
    float s = 0.f;
    for (int k = tid; k < TOT; k += stride) {
        unsigned u = smax[k];
        unsigned bits = (u & 0x80000000u) ? (u & 0x7FFFFFFFu) : ~u;
        s += __uint_as_float(bits) + h32[k];   // smax + h_a
    }

    #pragma unroll
    for (int off = 32; off > 0; off >>= 1)
        s += __shfl_down(s, off);

    __shared__ float redb[4];
    const int lane = threadIdx.x & 63, wave = threadIdx.x >> 6;
    if (lane == 0) redb[wave] = s;
    __syncthreads();
    if (threadIdx.x == 0) {
        float t = redb[0] + redb[1] + redb[2] + redb[3];
        // min_d = -2*(smax + h_a); loss = 0.005 * sum/32768
        atomicAdd(out, t * (-2.0f * 0.005f / 32768.f));
    }
}

extern "C" void kernel_launch(void* const* d_in, const int* in_sizes, int n_in,
                              void* d_out, int out_size, void* d_ws, size_t ws_size,
                              hipStream_t stream) {
    const float* x = (const float*)d_in[0];
    const float* y = (const float*)d_in[1];
    float* out = (float*)d_out;

    unsigned short* Aform = (unsigned short*)d_ws;                          // 2 MB
    unsigned short* Bform = (unsigned short*)((char*)d_ws + (2u << 20));    // 2 MB
    float*          h32   = (float*)((char*)d_ws + (4u << 20));             // 256 KB
    unsigned*       smax  = (unsigned*)((char*)d_ws + (4u << 20) + (256u << 10));

    prep_kernel<<<dim3(TOT / 256), dim3(256), 0, stream>>>(x, y, Aform, Bform, h32, smax, out);
    chamfer_mfma<<<dim3(512), dim3(256), 0, stream>>>(Aform, Bform, smax);
    reduce_kernel<<<dim3(64), dim3(256), 0, stream>>>(smax, h32, out);
}

// Round 9
// 73.427 us; speedup vs baseline: 1.3238x; 1.1782x over previous
//
#include <hip/hip_runtime.h>

#define NPTS 4096
#define NB   8
#define TOT  (2 * NB * NPTS)   // 65536 (i, dir*batch*point) rows

typedef __attribute__((ext_vector_type(8)))  short          bf16x8;
typedef __attribute__((ext_vector_type(8)))  unsigned short u16x8;
typedef __attribute__((ext_vector_type(16))) float          f32x16;

__device__ __forceinline__ unsigned short bf16_rne(float f) {
    unsigned u = __float_as_uint(f);
    u += 0x7FFFu + ((u >> 16) & 1u);
    return (unsigned short)(u >> 16);
}
__device__ __forceinline__ float bf16_f(unsigned short s) {
    return __uint_as_float(((unsigned)s) << 16);
}

// ---------------- pass 0: build fragment-ordered extended bf16 tiles -------
// s(i,j) = ah_i.bh_j + al_i.bh_j + ah_i.bl_j + 1*hh_j + 1*hl_j   (11 K-slots)
// (layout + numerics verified on-HW in R7: absmax ~0)
__global__ __launch_bounds__(256) void prep_kernel(
    const float* __restrict__ x, const float* __restrict__ y,
    unsigned short* __restrict__ Aform, unsigned short* __restrict__ Bform,
    float* __restrict__ h32, unsigned* __restrict__ smax,
    float* __restrict__ out)
{
    int i   = blockIdx.x * 256 + threadIdx.x;   // 0..65535
    int cid = i >> 12;                          // 0..7: x[b], 8..15: y[b]
    int p   = i & 4095;
    const float* src = (cid < 8) ? x + ((size_t)cid * NPTS + p) * 3
                                 : y + ((size_t)(cid - 8) * NPTS + p) * 3;
    float c0 = src[0], c1 = src[1], c2 = src[2];
    float h  = -0.5f * (c0 * c0 + c1 * c1 + c2 * c2);

    unsigned short h0 = bf16_rne(c0), h1 = bf16_rne(c1), h2 = bf16_rne(c2);
    unsigned short l0 = bf16_rne(c0 - bf16_f(h0));
    unsigned short l1 = bf16_rne(c1 - bf16_f(h1));
    unsigned short l2 = bf16_rne(c2 - bf16_f(h2));
    unsigned short hh = bf16_rne(h);
    unsigned short hl = bf16_rne(h - bf16_f(hh));
    const unsigned short ONE = 0x3F80;

    u16x8 alo, ahi, blo, bhi;
    alo[0]=h0; alo[1]=h1; alo[2]=h2; alo[3]=l0; alo[4]=l1; alo[5]=l2; alo[6]=h0; alo[7]=h1;
    ahi[0]=h2; ahi[1]=ONE; ahi[2]=ONE; ahi[3]=0; ahi[4]=0; ahi[5]=0; ahi[6]=0; ahi[7]=0;
    blo[0]=h0; blo[1]=h1; blo[2]=h2; blo[3]=h0; blo[4]=h1; blo[5]=h2; blo[6]=l0; blo[7]=l1;
    bhi[0]=l2; bhi[1]=hh; bhi[2]=hl; bhi[3]=0; bhi[4]=0; bhi[5]=0; bhi[6]=0; bhi[7]=0;

    int u = p >> 5, pos = p & 31;
    size_t base = ((size_t)cid << 17) + (size_t)u * 1024 + (size_t)pos * 16;
    *(u16x8*)((char*)Aform + base)       = alo;
    *(u16x8*)((char*)Aform + base + 512) = ahi;
    *(u16x8*)((char*)Bform + base)       = blo;
    *(u16x8*)((char*)Bform + base + 512) = bhi;

    h32[i]  = h;     // fp32 h_a for the epilogue (full precision)
    smax[i] = 0u;    // below any order-mapped float
    if (i == 0) *out = 0.f;
}

// ---------------- pass 1: MFMA chamfer core ----------------
// grid = 16 (dir,b) * 8 i-blocks * 4 j-quarters = 512 blocks of 256 thr.
// j-loop NOT unrolled (R7's unroll-2 hoisted 8 f32x16 MFMA dests -> spill).
// Epilogue in 2 phases of 2 tiles -> 33 KB LDS (R8's 66 KB crashed launch).
__global__ __launch_bounds__(256, 2) void chamfer_mfma(
    const unsigned short* __restrict__ Aform,
    const unsigned short* __restrict__ Bform,
    unsigned* __restrict__ smax)
{
    __shared__ float buf[4][64][33];   // 33792 B, per-wave regions

    const int bid  = blockIdx.x;
    const int dirb = bid >> 5;        // 0..15 (A-cloud id)
    const int sub  = bid & 31;
    const int iblk = sub >> 2;        // 0..7
    const int jq   = sub & 3;         // 0..3
    const int bcld = dirb ^ 8;        // B-cloud id (x<->y)

    const int tid = threadIdx.x;
    const int w   = tid >> 6;         // wave 0..3
    const int l   = tid & 63;
    const int g   = l >> 5;           // k-half
    const int pos = l & 31;           // row/col within tile

    const char* Abase = (const char*)Aform + ((size_t)dirb << 17);
    const char* Bbase = (const char*)Bform + ((size_t)bcld << 17);

    // A fragments: i-tiles iblk*16 + w*4 + t (loaded once, reused for all j)
    const int it0 = iblk * 16 + w * 4;
    bf16x8 afr[4];
    #pragma unroll
    for (int t = 0; t < 4; ++t)
        afr[t] = *(const bf16x8*)(Abase + (size_t)(it0 + t) * 1024
                                        + (size_t)g * 512 + (size_t)pos * 16);

    f32x16 zc;
    #pragma unroll
    for (int r = 0; r < 16; ++r) zc[r] = 0.f;

    f32x16 run[4];
    #pragma unroll
    for (int t = 0; t < 4; ++t)
        #pragma unroll
        for (int r = 0; r < 16; ++r) run[t][r] = -3.0e38f;

    const char* Bq = Bbase + (size_t)(jq * 32) * 1024
                           + (size_t)g * 512 + (size_t)pos * 16;

    bf16x8 cb0 = *(const bf16x8*)(Bq);
    bf16x8 cb1 = *(const bf16x8*)(Bq + 1024);

    #pragma unroll 1
    for (int j = 0; j < 32; j += 2) {
        const int jn = (j + 2) & 31;           // branchless 2-deep prefetch
        bf16x8 nb0 = *(const bf16x8*)(Bq + (size_t)jn * 1024);
        bf16x8 nb1 = *(const bf16x8*)(Bq + (size_t)jn * 1024 + 1024);
        #pragma unroll
        for (int t = 0; t < 4; ++t) {
            f32x16 d0 = __builtin_amdgcn_mfma_f32_32x32x16_bf16(afr[t], cb0, zc, 0, 0, 0);
            f32x16 d1 = __builtin_amdgcn_mfma_f32_32x32x16_bf16(afr[t], cb1, zc, 0, 0, 0);
            #pragma unroll
            for (int r = 0; r < 16; ++r)
                run[t][r] = fmaxf(fmaxf(d0[r], d1[r]), run[t][r]);   // v_max3_f32
        }
        cb0 = nb0; cb1 = nb1;
    }

    // ---- epilogue, 2 phases of 2 i-tiles each (33 KB LDS) ----
    #pragma unroll
    for (int ph = 0; ph < 2; ++ph) {
        if (ph) __syncthreads();   // phase-1 reads done before overwrite
        #pragma unroll
        for (int tl = 0; tl < 2; ++tl) {
            const int t = 2 * ph + tl;
            #pragma unroll
            for (int r = 0; r < 16; ++r) {
                int rowin = (r & 3) + 8 * (r >> 2) + 4 * g;   // verified C/D map
                buf[w][tl * 32 + rowin][pos] = run[t][r];
            }
        }
        __syncthreads();

        // thread l reduces local row l (stride 33 -> every bank 2-way = free)
        float m = buf[w][l][0];
        #pragma unroll
        for (int k = 1; k < 32; ++k) m = fmaxf(m, buf[w][l][k]);
        // local row l = tl*32 + rowin; global t = 2*ph + tl
        int idx = dirb * 4096 + iblk * 512 + w * 128 + 2 * ph * 32 + l;
        unsigned bits = __float_as_uint(m);
        unsigned mu = (bits & 0x80000000u) ? ~bits : (bits | 0x80000000u);
        atomicMax(&smax[idx], mu);
    }
}

// ---------------- pass 2: unmap, add h_a, sum ----------------
__global__ __launch_bounds__(256) void reduce_kernel(
    const unsigned* __restrict__ smax,
    const float* __restrict__ h32,
    float* __restrict__ out)
{
    const int stride = 64 * 256;
    int tid = blockIdx.x * 256 + threadIdx.x;
    float s = 0.f;
    for (int k = tid; k < TOT; k += stride) {
        unsigned u = smax[k];
        unsigned bits = (u & 0x80000000u) ? (u & 0x7FFFFFFFu) : ~u;
        s += __uint_as_float(bits) + h32[k];   // smax + h_a
    }

    #pragma unroll
    for (int off = 32; off > 0; off >>= 1)
        s += __shfl_down(s, off);

    __shared__ float redb[4];
    const int lane = threadIdx.x & 63, wave = threadIdx.x >> 6;
    if (lane == 0) redb[wave] = s;
    __syncthreads();
    if (threadIdx.x == 0) {
        float t = redb[0] + redb[1] + redb[2] + redb[3];
        // min_d = -2*(smax + h_a); loss = 0.005 * sum/32768
        atomicAdd(out, t * (-2.0f * 0.005f / 32768.f));
    }
}

extern "C" void kernel_launch(void* const* d_in, const int* in_sizes, int n_in,
                              void* d_out, int out_size, void* d_ws, size_t ws_size,
                              hipStream_t stream) {
    const float* x = (const float*)d_in[0];
    const float* y = (const float*)d_in[1];
    float* out = (float*)d_out;

    unsigned short* Aform = (unsigned short*)d_ws;                          // 2 MB
    unsigned short* Bform = (unsigned short*)((char*)d_ws + (2u << 20));    // 2 MB
    float*          h32   = (float*)((char*)d_ws + (4u << 20));             // 256 KB
    unsigned*       smax  = (unsigned*)((char*)d_ws + (4u << 20) + (256u << 10));

    prep_kernel<<<dim3(TOT / 256), dim3(256), 0, stream>>>(x, y, Aform, Bform, h32, smax, out);
    chamfer_mfma<<<dim3(512), dim3(256), 0, stream>>>(Aform, Bform, smax);
    reduce_kernel<<<dim3(64), dim3(256), 0, stream>>>(smax, h32, out);
}